// Round 2
// baseline (576.884 us; speedup 1.0000x reference)
//
#include <hip/hip_runtime.h>
#include <hip/hip_bf16.h>

// DCNv2 CrossNet on MI355X — fully fused: all 3 cross layers in ONE kernel.
// x_l lives in fp32 registers (MFMA-ownership layout) + bf16 LDS copy;
// x0 lives in packed-bf16 registers. Only global traffic: read x, write out,
// stream pre-swizzled bf16 weight fragments from L2 (1.6 MB working set).
//
// Shapes: x[32768,512]; Vs[3,4,64,512]; Cs[3,4,64,64]; Us[3,4,512,64];
//         bias[3,512]; gate_w[512,4].

#define CROSS   3
#define ENUM    4
#define LR      64
#define ELD     256     // ENUM*LR
#define DIM     512
#define BATCH   32768
#define BT      32      // batch rows per block
#define NTHR    256     // 4 waves

#define XL_W    520     // 512 + 8 pad
#define Y_W     264     // 256 + 8 pad

typedef __bf16 bf16x8 __attribute__((ext_vector_type(8)));
typedef float  f32x4  __attribute__((ext_vector_type(4)));
typedef unsigned short us;

__device__ __forceinline__ us f2bf(float f) {
    return __builtin_bit_cast(us, (__bf16)f);
}
__device__ __forceinline__ float bf2f(us b) {
    unsigned int u = ((unsigned int)b) << 16;
    return __builtin_bit_cast(float, u);
}
// fast tanh: (e^2x - 1) / (e^2x + 1). Inputs bounded (~|x|<15) by the
// 0.05-scaled weights, so no overflow handling needed.
__device__ __forceinline__ float tanh_fast(float x) {
    float t = __expf(2.f * x);
    return (t - 1.f) * __builtin_amdgcn_rcpf(t + 1.f);
}

#define MFMA(a, b, c) __builtin_amdgcn_mfma_f32_16x16x32_bf16(a, b, c, 0, 0, 0)

// ---------------------------------------------------------------------------
// Single swizzle prepass: fp32 weights -> bf16 MFMA-B fragment order
// frag[nt][ks][lane][8]: n = nt*16 + (lane&15), k = ks*32 + (lane>>4)*8 + j.
// Block ranges: V [0,768), U [768,1536), C [1536,1632), gate [1632,1648).
// ---------------------------------------------------------------------------
__global__ __launch_bounds__(64) void swz_all(
    const float* __restrict__ Vs, const float* __restrict__ Cs,
    const float* __restrict__ Us, const float* __restrict__ gw,
    us* __restrict__ Vf, us* __restrict__ Cf,
    us* __restrict__ Uf, us* __restrict__ Gf)
{
    int b = blockIdx.x;
    int lane = threadIdx.x;
    if (b < 768) {                       // V: [3][16 nt][16 ks]
        int i = b >> 8, t = b & 255;
        int nt = t >> 4, ks = t & 15;
        int n  = nt * 16 + (lane & 15);
        int k0 = ks * 32 + (lane >> 4) * 8;
        const float* src = Vs + (size_t)i * ELD * DIM + (size_t)n * DIM + k0;
        us* dst = Vf + (size_t)i * ELD * DIM
                + ((size_t)(nt * 16 + ks) * 64 + lane) * 8;
        #pragma unroll
        for (int j = 0; j < 8; ++j) dst[j] = f2bf(src[j]);
    } else if (b < 1536) {               // U': [3][32 nt][8 ks], k = e*64+l
        int bb = b - 768;
        int i = bb >> 8, t = bb & 255;
        int nt = t >> 3, ks = t & 7;
        int n  = nt * 16 + (lane & 15);            // d
        int k0 = ks * 32 + (lane >> 4) * 8;        // e*64 + l
        int e = k0 >> 6, l0 = k0 & 63;
        const float* src = Us + (size_t)i * ENUM * DIM * LR
                         + (size_t)e * DIM * LR + (size_t)n * LR + l0;
        us* dst = Uf + (size_t)i * DIM * ELD
                + ((size_t)(nt * 8 + ks) * 64 + lane) * 8;
        #pragma unroll
        for (int j = 0; j < 8; ++j) dst[j] = f2bf(src[j]);
    } else if (b < 1632) {               // C: [3][4 e][4 nt][2 ks]
        int bb = b - 1536;
        int i = bb >> 5, rest = bb & 31;
        int e = rest >> 3, t = rest & 7;
        int nt = t >> 1, ks = t & 1;
        int n  = nt * 16 + (lane & 15);
        int k0 = ks * 32 + (lane >> 4) * 8;
        const float* src = Cs + (((size_t)(i * ENUM + e) * LR + n) * LR) + k0;
        us* dst = Cf + (size_t)i * ENUM * LR * LR
                + ((size_t)((e * 4 + nt) * 2 + ks) * 64 + lane) * 8;
        #pragma unroll
        for (int j = 0; j < 8; ++j) dst[j] = f2bf(src[j]);
    } else {                             // gate: [16 ks], n<4 real, rest 0
        int ks = b - 1632;
        int n  = lane & 15;
        int k0 = ks * 32 + (lane >> 4) * 8;
        us* dst = Gf + ((size_t)ks * 64 + lane) * 8;
        #pragma unroll
        for (int j = 0; j < 8; ++j)
            dst[j] = (n < ENUM) ? f2bf(gw[(size_t)(k0 + j) * ENUM + n]) : (us)0;
    }
}

// ---------------------------------------------------------------------------
// Fused 3-layer kernel. Block: 32 rows, 256 threads (4 waves).
// Ownership (matches 16x16x32 D-layout): row = mt*16 + quad*4 + r,
// col = (wave*8 + nt)*16 + nl. Wave w owns GEMM1 cols [w*64,+64), expert w
// in GEMM2, GEMM3 cols [w*128,+128).
// ---------------------------------------------------------------------------
__global__ __launch_bounds__(NTHR) void dcn_fused(
    const float* __restrict__ x,
    float* __restrict__ out,
    const us* __restrict__ Vf,
    const us* __restrict__ Cf,
    const us* __restrict__ Uf,
    const us* __restrict__ Gf,
    const float* __restrict__ bias)
{
    __shared__ us xl_s[BT * XL_W];       // x_l bf16 (restaged per layer)
    __shared__ us y_s[BT * Y_W];         // Y, then z (in place)
    __shared__ float g_s[BT * ENUM];     // gate scores

    const int tid  = threadIdx.x;
    const int wave = tid >> 6, lane = tid & 63;
    const int quad = lane >> 4, nl = lane & 15;
    const int row0 = blockIdx.x * BT;

    // ---- initial load: x -> xl regs (fp32 master) + x0 packed bf16 + xl_s
    float xl[2][8][4];
    unsigned int x0p[2][8][2];
    {
        const float* xb = x + (size_t)(row0 + quad * 4) * DIM + wave * 128 + nl;
        #pragma unroll
        for (int mt = 0; mt < 2; ++mt)
            #pragma unroll
            for (int nt = 0; nt < 8; ++nt)
                #pragma unroll
                for (int r = 0; r < 4; ++r)
                    xl[mt][nt][r] = xb[(size_t)(mt * 16 + r) * DIM + nt * 16];
        #pragma unroll
        for (int mt = 0; mt < 2; ++mt)
            #pragma unroll
            for (int nt = 0; nt < 8; ++nt)
                #pragma unroll
                for (int j = 0; j < 2; ++j)
                    x0p[mt][nt][j] =
                        (unsigned int)f2bf(xl[mt][nt][2 * j])
                      | ((unsigned int)f2bf(xl[mt][nt][2 * j + 1]) << 16);
        #pragma unroll
        for (int mt = 0; mt < 2; ++mt)
            #pragma unroll
            for (int nt = 0; nt < 8; ++nt)
                #pragma unroll
                for (int r = 0; r < 4; ++r)
                    xl_s[(mt * 16 + quad * 4 + r) * XL_W
                         + wave * 128 + nt * 16 + nl] = f2bf(xl[mt][nt][r]);
    }
    __syncthreads();

    #pragma unroll 1
    for (int layer = 0; layer < CROSS; ++layer) {
        const us* Vl = Vf + (size_t)layer * ELD * DIM;
        const us* Cl = Cf + (size_t)layer * ENUM * LR * LR;
        const us* Ul = Uf + (size_t)layer * DIM * ELD;
        const float* bl = bias + layer * DIM;

        // ---- GEMM1: Y = tanh(xl @ V^T); wave 0 also computes gate scores
        f32x4 acc1[2][4];
        f32x4 gacc[2];
        #pragma unroll
        for (int mt = 0; mt < 2; ++mt) {
            gacc[mt] = (f32x4)0.f;
            #pragma unroll
            for (int nt = 0; nt < 4; ++nt) acc1[mt][nt] = (f32x4)0.f;
        }
        #pragma unroll 4
        for (int ks = 0; ks < 16; ++ks) {
            bf16x8 a0 = *reinterpret_cast<const bf16x8*>(
                &xl_s[nl * XL_W + ks * 32 + quad * 8]);
            bf16x8 a1 = *reinterpret_cast<const bf16x8*>(
                &xl_s[(16 + nl) * XL_W + ks * 32 + quad * 8]);
            #pragma unroll
            for (int nt = 0; nt < 4; ++nt) {
                bf16x8 bfr = *reinterpret_cast<const bf16x8*>(
                    &Vl[((size_t)((wave * 4 + nt) * 16 + ks) * 64 + lane) * 8]);
                acc1[0][nt] = MFMA(a0, bfr, acc1[0][nt]);
                acc1[1][nt] = MFMA(a1, bfr, acc1[1][nt]);
            }
            if (wave == 0) {
                bf16x8 bg = *reinterpret_cast<const bf16x8*>(
                    &Gf[((size_t)ks * 64 + lane) * 8]);
                gacc[0] = MFMA(a0, bg, gacc[0]);
                gacc[1] = MFMA(a1, bg, gacc[1]);
            }
        }
        #pragma unroll
        for (int mt = 0; mt < 2; ++mt)
            #pragma unroll
            for (int r = 0; r < 4; ++r) {
                int row = mt * 16 + quad * 4 + r;
                #pragma unroll
                for (int nt = 0; nt < 4; ++nt)
                    y_s[row * Y_W + wave * 64 + nt * 16 + nl] =
                        f2bf(tanh_fast(acc1[mt][nt][r]));
            }
        if (wave == 0 && nl < ENUM) {
            #pragma unroll
            for (int mt = 0; mt < 2; ++mt)
                #pragma unroll
                for (int r = 0; r < 4; ++r)
                    g_s[(mt * 16 + quad * 4 + r) * ENUM + nl] = gacc[mt][r];
        }
        __syncthreads();

        // ---- GEMM2: z = g ⊙ tanh(Y_e @ C_e^T), in place (wave e owns its cols)
        f32x4 acc2[2][4];
        #pragma unroll
        for (int mt = 0; mt < 2; ++mt)
            #pragma unroll
            for (int nt = 0; nt < 4; ++nt) acc2[mt][nt] = (f32x4)0.f;
        #pragma unroll
        for (int ks = 0; ks < 2; ++ks) {
            bf16x8 a0 = *reinterpret_cast<const bf16x8*>(
                &y_s[nl * Y_W + wave * 64 + ks * 32 + quad * 8]);
            bf16x8 a1 = *reinterpret_cast<const bf16x8*>(
                &y_s[(16 + nl) * Y_W + wave * 64 + ks * 32 + quad * 8]);
            #pragma unroll
            for (int nt = 0; nt < 4; ++nt) {
                bf16x8 bfr = *reinterpret_cast<const bf16x8*>(
                    &Cl[((size_t)((wave * 4 + nt) * 2 + ks) * 64 + lane) * 8]);
                acc2[0][nt] = MFMA(a0, bfr, acc2[0][nt]);
                acc2[1][nt] = MFMA(a1, bfr, acc2[1][nt]);
            }
        }
        #pragma unroll
        for (int mt = 0; mt < 2; ++mt)
            #pragma unroll
            for (int r = 0; r < 4; ++r) {
                int row = mt * 16 + quad * 4 + r;
                float gv = g_s[row * ENUM + wave];
                #pragma unroll
                for (int nt = 0; nt < 4; ++nt)
                    y_s[row * Y_W + wave * 64 + nt * 16 + nl] =
                        f2bf(tanh_fast(acc2[mt][nt][r]) * gv);
            }
        __syncthreads();

        // ---- GEMM3: core = z @ U'^T  (K = 256)
        f32x4 acc3[2][8];
        #pragma unroll
        for (int mt = 0; mt < 2; ++mt)
            #pragma unroll
            for (int nt = 0; nt < 8; ++nt) acc3[mt][nt] = (f32x4)0.f;
        #pragma unroll 2
        for (int ks = 0; ks < 8; ++ks) {
            bf16x8 a0 = *reinterpret_cast<const bf16x8*>(
                &y_s[nl * Y_W + ks * 32 + quad * 8]);
            bf16x8 a1 = *reinterpret_cast<const bf16x8*>(
                &y_s[(16 + nl) * Y_W + ks * 32 + quad * 8]);
            #pragma unroll
            for (int nt = 0; nt < 8; ++nt) {
                bf16x8 bfr = *reinterpret_cast<const bf16x8*>(
                    &Ul[((size_t)((wave * 8 + nt) * 8 + ks) * 64 + lane) * 8]);
                acc3[0][nt] = MFMA(a0, bfr, acc3[0][nt]);
                acc3[1][nt] = MFMA(a1, bfr, acc3[1][nt]);
            }
        }

        // ---- epilogue: xl += x0 * (core + bias*G)   (all in registers)
        float Gv[2][4];
        #pragma unroll
        for (int mt = 0; mt < 2; ++mt)
            #pragma unroll
            for (int r = 0; r < 4; ++r) {
                int row = mt * 16 + quad * 4 + r;
                f32x4 g4 = *reinterpret_cast<const f32x4*>(&g_s[row * ENUM]);
                Gv[mt][r] = g4[0] + g4[1] + g4[2] + g4[3];
            }
        #pragma unroll
        for (int nt = 0; nt < 8; ++nt) {
            int col = wave * 128 + nt * 16 + nl;
            float bc = bl[col];
            #pragma unroll
            for (int mt = 0; mt < 2; ++mt)
                #pragma unroll
                for (int r = 0; r < 4; ++r) {
                    float x0v = bf2f((us)(x0p[mt][nt][r >> 1] >> ((r & 1) * 16)));
                    xl[mt][nt][r] += x0v * (acc3[mt][nt][r] + bc * Gv[mt][r]);
                }
        }

        // ---- restage xl -> LDS bf16 for next layer
        if (layer < CROSS - 1) {
            #pragma unroll
            for (int mt = 0; mt < 2; ++mt)
                #pragma unroll
                for (int nt = 0; nt < 8; ++nt)
                    #pragma unroll
                    for (int r = 0; r < 4; ++r)
                        xl_s[(mt * 16 + quad * 4 + r) * XL_W
                             + wave * 128 + nt * 16 + nl] = f2bf(xl[mt][nt][r]);
            __syncthreads();
        }
    }

    // ---- final store (fp32, ownership layout: 4x64B coalesced per instr)
    float* ob = out + (size_t)(row0 + quad * 4) * DIM + wave * 128 + nl;
    #pragma unroll
    for (int mt = 0; mt < 2; ++mt)
        #pragma unroll
        for (int nt = 0; nt < 8; ++nt)
            #pragma unroll
            for (int r = 0; r < 4; ++r)
                ob[(size_t)(mt * 16 + r) * DIM + nt * 16] = xl[mt][nt][r];
}

// ---------------------------------------------------------------------------
extern "C" void kernel_launch(void* const* d_in, const int* in_sizes, int n_in,
                              void* d_out, int out_size, void* d_ws,
                              size_t ws_size, hipStream_t stream) {
    const float* x      = (const float*)d_in[0];
    const float* Vs     = (const float*)d_in[1];
    const float* Cs     = (const float*)d_in[2];
    const float* Us     = (const float*)d_in[3];
    const float* bias   = (const float*)d_in[4];
    const float* gate_w = (const float*)d_in[5];
    float* out = (float*)d_out;

    us* Vf = (us*)d_ws;                                   // 393216 bf16
    us* Uf = Vf + (size_t)CROSS * ELD * DIM;              // 393216
    us* Cf = Uf + (size_t)CROSS * DIM * ELD;              // 49152
    us* Gf = Cf + (size_t)CROSS * ENUM * LR * LR;         // 8192

    swz_all<<<1648, 64, 0, stream>>>(Vs, Cs, Us, gate_w, Vf, Cf, Uf, Gf);
    dcn_fused<<<BATCH / BT, NTHR, 0, stream>>>(x, out, Vf, Cf, Uf, Gf, bias);
}

// Round 3
// 442.358 us; speedup vs baseline: 1.3041x; 1.3041x over previous
//
#include <hip/hip_runtime.h>
#include <hip/hip_bf16.h>

// DCNv2 CrossNet on MI355X — fully fused, occupancy-first version.
// x_l master lives as bf16 in XOR-swizzled LDS (no fp32 register master);
// x0 packed bf16 in 16 VGPRs; GEMM3 split into two N-halves to halve
// accumulator pressure. Target: 3 blocks (12 waves)/CU resident so the
// L2 weight-fragment stream latency is overlapped.
//
// Shapes: x[32768,512]; Vs[3,4,64,512]; Cs[3,4,64,64]; Us[3,4,512,64];
//         bias[3,512]; gate_w[512,4].

#define CROSS   3
#define ENUM    4
#define LR      64
#define ELD     256     // ENUM*LR
#define DIM     512
#define BATCH   32768
#define BT      32      // batch rows per block
#define NTHR    256     // 4 waves

typedef __bf16 bf16x8 __attribute__((ext_vector_type(8)));
typedef float  f32x4  __attribute__((ext_vector_type(4)));
typedef unsigned short us;

__device__ __forceinline__ us f2bf(float f) {
    return __builtin_bit_cast(us, (__bf16)f);
}
__device__ __forceinline__ float bf2f(us b) {
    unsigned int u = ((unsigned int)b) << 16;
    return __builtin_bit_cast(float, u);
}
// fast tanh: (e^2x - 1) / (e^2x + 1); inputs bounded by 0.05-scaled weights.
__device__ __forceinline__ float tanh_fast(float x) {
    float t = __expf(2.f * x);
    return (t - 1.f) * __builtin_amdgcn_rcpf(t + 1.f);
}

// XOR-swizzled LDS indices (row strides 512/256 shorts == 0 mod 32 banks;
// 16B chunk index XORed with row&7 -> conflict-free b128 A-fragment reads).
__device__ __forceinline__ int xidx(int row, int col) {   // xl_s [32][512]
    return (row << 9) + ((((col >> 3) ^ (row & 7)) << 3) | (col & 7));
}
__device__ __forceinline__ int yidx(int row, int col) {   // y_s [32][256]
    return (row << 8) + ((((col >> 3) ^ (row & 7)) << 3) | (col & 7));
}

#define MFMA(a, b, c) __builtin_amdgcn_mfma_f32_16x16x32_bf16(a, b, c, 0, 0, 0)

// ---------------------------------------------------------------------------
// Swizzle prepass: fp32 weights -> bf16 MFMA-B fragment order
// frag[nt][ks][lane][8]: n = nt*16 + (lane&15), k = ks*32 + (lane>>4)*8 + j.
// ---------------------------------------------------------------------------
__global__ __launch_bounds__(64) void swz_all(
    const float* __restrict__ Vs, const float* __restrict__ Cs,
    const float* __restrict__ Us, const float* __restrict__ gw,
    us* __restrict__ Vf, us* __restrict__ Cf,
    us* __restrict__ Uf, us* __restrict__ Gf)
{
    int b = blockIdx.x;
    int lane = threadIdx.x;
    if (b < 768) {                       // V: [3][16 nt][16 ks]
        int i = b >> 8, t = b & 255;
        int nt = t >> 4, ks = t & 15;
        int n  = nt * 16 + (lane & 15);
        int k0 = ks * 32 + (lane >> 4) * 8;
        const float* src = Vs + (size_t)i * ELD * DIM + (size_t)n * DIM + k0;
        us* dst = Vf + (size_t)i * ELD * DIM
                + ((size_t)(nt * 16 + ks) * 64 + lane) * 8;
        #pragma unroll
        for (int j = 0; j < 8; ++j) dst[j] = f2bf(src[j]);
    } else if (b < 1536) {               // U': [3][32 nt][8 ks], k = e*64+l
        int bb = b - 768;
        int i = bb >> 8, t = bb & 255;
        int nt = t >> 3, ks = t & 7;
        int n  = nt * 16 + (lane & 15);            // d
        int k0 = ks * 32 + (lane >> 4) * 8;        // e*64 + l
        int e = k0 >> 6, l0 = k0 & 63;
        const float* src = Us + (size_t)i * ENUM * DIM * LR
                         + (size_t)e * DIM * LR + (size_t)n * LR + l0;
        us* dst = Uf + (size_t)i * DIM * ELD
                + ((size_t)(nt * 8 + ks) * 64 + lane) * 8;
        #pragma unroll
        for (int j = 0; j < 8; ++j) dst[j] = f2bf(src[j]);
    } else if (b < 1632) {               // C: [3][4 e][4 nt][2 ks]
        int bb = b - 1536;
        int i = bb >> 5, rest = bb & 31;
        int e = rest >> 3, t = rest & 7;
        int nt = t >> 1, ks = t & 1;
        int n  = nt * 16 + (lane & 15);
        int k0 = ks * 32 + (lane >> 4) * 8;
        const float* src = Cs + (((size_t)(i * ENUM + e) * LR + n) * LR) + k0;
        us* dst = Cf + (size_t)i * ENUM * LR * LR
                + ((size_t)((e * 4 + nt) * 2 + ks) * 64 + lane) * 8;
        #pragma unroll
        for (int j = 0; j < 8; ++j) dst[j] = f2bf(src[j]);
    } else {                             // gate: [16 ks], n<4 real, rest 0
        int ks = b - 1632;
        int n  = lane & 15;
        int k0 = ks * 32 + (lane >> 4) * 8;
        us* dst = Gf + ((size_t)ks * 64 + lane) * 8;
        #pragma unroll
        for (int j = 0; j < 8; ++j)
            dst[j] = (n < ENUM) ? f2bf(gw[(size_t)(k0 + j) * ENUM + n]) : (us)0;
    }
}

// ---------------------------------------------------------------------------
// Fused 3-layer kernel. Block: 32 rows, 256 threads (4 waves).
// Thread ownership (16x16x32 D-layout): row = mt*16 + quad*4 + r,
// col = (wave*8 + nt)*16 + nl. Wave w owns GEMM1 cols [w*64,+64),
// expert w in GEMM2, GEMM3 cols [w*128,+128).
// ---------------------------------------------------------------------------
__global__ __launch_bounds__(NTHR, 3) void dcn_fused(
    const float* __restrict__ x,
    float* __restrict__ out,
    const us* __restrict__ Vf,
    const us* __restrict__ Cf,
    const us* __restrict__ Uf,
    const us* __restrict__ Gf,
    const float* __restrict__ bias)
{
    __shared__ us xl_s[BT * DIM];        // x_l master, bf16, swizzled (32 KB)
    __shared__ us y_s[BT * ELD];         // Y then z, swizzled (16 KB)
    __shared__ float g_s[BT * ENUM];     // gate scores (512 B)

    const int tid  = threadIdx.x;
    const int wave = tid >> 6, lane = tid & 63;
    const int quad = lane >> 4, nl = lane & 15;
    const int row0 = blockIdx.x * BT;

    // ---- stage x: x0 packed-bf16 regs + xl_s master (bf16, swizzled)
    unsigned int x0p[2][8][2];
    {
        const float* xb = x + (size_t)(row0 + quad * 4) * DIM + wave * 128 + nl;
        #pragma unroll
        for (int mt = 0; mt < 2; ++mt)
            #pragma unroll
            for (int nt = 0; nt < 8; ++nt) {
                float v0 = xb[(size_t)(mt * 16 + 0) * DIM + nt * 16];
                float v1 = xb[(size_t)(mt * 16 + 1) * DIM + nt * 16];
                float v2 = xb[(size_t)(mt * 16 + 2) * DIM + nt * 16];
                float v3 = xb[(size_t)(mt * 16 + 3) * DIM + nt * 16];
                us b0 = f2bf(v0), b1 = f2bf(v1), b2 = f2bf(v2), b3 = f2bf(v3);
                x0p[mt][nt][0] = (unsigned int)b0 | ((unsigned int)b1 << 16);
                x0p[mt][nt][1] = (unsigned int)b2 | ((unsigned int)b3 << 16);
                int rb = mt * 16 + quad * 4;
                int col = wave * 128 + nt * 16 + nl;
                xl_s[xidx(rb + 0, col)] = b0;
                xl_s[xidx(rb + 1, col)] = b1;
                xl_s[xidx(rb + 2, col)] = b2;
                xl_s[xidx(rb + 3, col)] = b3;
            }
    }
    __syncthreads();

    #pragma unroll 1
    for (int layer = 0; layer < CROSS; ++layer) {
        const us* Vl = Vf + (size_t)layer * ELD * DIM;
        const us* Cl = Cf + (size_t)layer * ENUM * LR * LR;
        const us* Ul = Uf + (size_t)layer * DIM * ELD;
        const float* bl = bias + layer * DIM;

        // ---- GEMM1: Y = tanh(xl @ V^T); wave 0 also computes gate scores
        f32x4 acc1[2][4];
        f32x4 gacc[2];
        #pragma unroll
        for (int mt = 0; mt < 2; ++mt) {
            gacc[mt] = (f32x4)0.f;
            #pragma unroll
            for (int nt = 0; nt < 4; ++nt) acc1[mt][nt] = (f32x4)0.f;
        }
        #pragma unroll 4
        for (int ks = 0; ks < 16; ++ks) {
            bf16x8 a0 = *reinterpret_cast<const bf16x8*>(
                &xl_s[xidx(nl, ks * 32 + quad * 8)]);
            bf16x8 a1 = *reinterpret_cast<const bf16x8*>(
                &xl_s[xidx(16 + nl, ks * 32 + quad * 8)]);
            #pragma unroll
            for (int nt = 0; nt < 4; ++nt) {
                bf16x8 bfr = *reinterpret_cast<const bf16x8*>(
                    &Vl[((size_t)((wave * 4 + nt) * 16 + ks) * 64 + lane) * 8]);
                acc1[0][nt] = MFMA(a0, bfr, acc1[0][nt]);
                acc1[1][nt] = MFMA(a1, bfr, acc1[1][nt]);
            }
            if (wave == 0) {
                bf16x8 bg = *reinterpret_cast<const bf16x8*>(
                    &Gf[((size_t)ks * 64 + lane) * 8]);
                gacc[0] = MFMA(a0, bg, gacc[0]);
                gacc[1] = MFMA(a1, bg, gacc[1]);
            }
        }
        #pragma unroll
        for (int mt = 0; mt < 2; ++mt)
            #pragma unroll
            for (int r = 0; r < 4; ++r) {
                int row = mt * 16 + quad * 4 + r;
                #pragma unroll
                for (int nt = 0; nt < 4; ++nt)
                    y_s[yidx(row, wave * 64 + nt * 16 + nl)] =
                        f2bf(tanh_fast(acc1[mt][nt][r]));
            }
        if (wave == 0 && nl < ENUM) {
            #pragma unroll
            for (int mt = 0; mt < 2; ++mt)
                #pragma unroll
                for (int r = 0; r < 4; ++r)
                    g_s[(mt * 16 + quad * 4 + r) * ENUM + nl] = gacc[mt][r];
        }
        __syncthreads();

        // ---- GEMM2: z = g ⊙ tanh(Y_e @ C_e^T), in place (wave-local cols)
        f32x4 acc2[2][4];
        #pragma unroll
        for (int mt = 0; mt < 2; ++mt)
            #pragma unroll
            for (int nt = 0; nt < 4; ++nt) acc2[mt][nt] = (f32x4)0.f;
        #pragma unroll
        for (int ks = 0; ks < 2; ++ks) {
            bf16x8 a0 = *reinterpret_cast<const bf16x8*>(
                &y_s[yidx(nl, wave * 64 + ks * 32 + quad * 8)]);
            bf16x8 a1 = *reinterpret_cast<const bf16x8*>(
                &y_s[yidx(16 + nl, wave * 64 + ks * 32 + quad * 8)]);
            #pragma unroll
            for (int nt = 0; nt < 4; ++nt) {
                bf16x8 bfr = *reinterpret_cast<const bf16x8*>(
                    &Cl[((size_t)((wave * 4 + nt) * 2 + ks) * 64 + lane) * 8]);
                acc2[0][nt] = MFMA(a0, bfr, acc2[0][nt]);
                acc2[1][nt] = MFMA(a1, bfr, acc2[1][nt]);
            }
        }
        #pragma unroll
        for (int mt = 0; mt < 2; ++mt)
            #pragma unroll
            for (int r = 0; r < 4; ++r) {
                int row = mt * 16 + quad * 4 + r;
                float gv = g_s[row * ENUM + wave];
                #pragma unroll
                for (int nt = 0; nt < 4; ++nt)
                    y_s[yidx(row, wave * 64 + nt * 16 + nl)] =
                        f2bf(tanh_fast(acc2[mt][nt][r]) * gv);
            }
        __syncthreads();

        // ---- Gv (sum of gate scores per row)
        float Gv[2][4];
        #pragma unroll
        for (int mt = 0; mt < 2; ++mt)
            #pragma unroll
            for (int r = 0; r < 4; ++r) {
                int row = mt * 16 + quad * 4 + r;
                f32x4 g4 = *reinterpret_cast<const f32x4*>(&g_s[row * ENUM]);
                Gv[mt][r] = g4[0] + g4[1] + g4[2] + g4[3];
            }

        // ---- GEMM3 in two N-halves (32 accumulator VGPRs each) + epilogue
        #pragma unroll 1
        for (int half = 0; half < 2; ++half) {
            f32x4 acc3[2][4];
            #pragma unroll
            for (int mt = 0; mt < 2; ++mt)
                #pragma unroll
                for (int nt = 0; nt < 4; ++nt) acc3[mt][nt] = (f32x4)0.f;
            #pragma unroll 4
            for (int ks = 0; ks < 8; ++ks) {
                bf16x8 a0 = *reinterpret_cast<const bf16x8*>(
                    &y_s[yidx(nl, ks * 32 + quad * 8)]);
                bf16x8 a1 = *reinterpret_cast<const bf16x8*>(
                    &y_s[yidx(16 + nl, ks * 32 + quad * 8)]);
                #pragma unroll
                for (int nt2 = 0; nt2 < 4; ++nt2) {
                    int nt = half * 4 + nt2;
                    bf16x8 bfr = *reinterpret_cast<const bf16x8*>(
                        &Ul[((size_t)((wave * 8 + nt) * 8 + ks) * 64 + lane) * 8]);
                    acc3[0][nt2] = MFMA(a0, bfr, acc3[0][nt2]);
                    acc3[1][nt2] = MFMA(a1, bfr, acc3[1][nt2]);
                }
            }
            // epilogue: xl = xl + x0 * (core + bias*G)
            #pragma unroll
            for (int nt2 = 0; nt2 < 4; ++nt2) {
                int nt = half * 4 + nt2;
                int col = wave * 128 + nt * 16 + nl;
                float bc = bl[col];
                #pragma unroll
                for (int mt = 0; mt < 2; ++mt)
                    #pragma unroll
                    for (int r = 0; r < 4; ++r) {
                        int row = mt * 16 + quad * 4 + r;
                        float x0v = bf2f(
                            (us)(x0p[mt][nt][r >> 1] >> ((r & 1) * 16)));
                        float xlo = bf2f(xl_s[xidx(row, col)]);
                        float res = xlo
                                  + x0v * (acc3[mt][nt2][r] + bc * Gv[mt][r]);
                        if (layer == CROSS - 1)
                            out[(size_t)(row0 + row) * DIM + col] = res;
                        else
                            xl_s[xidx(row, col)] = f2bf(res);
                    }
            }
        }
        if (layer < CROSS - 1) __syncthreads();
    }
}

// ---------------------------------------------------------------------------
extern "C" void kernel_launch(void* const* d_in, const int* in_sizes, int n_in,
                              void* d_out, int out_size, void* d_ws,
                              size_t ws_size, hipStream_t stream) {
    const float* x      = (const float*)d_in[0];
    const float* Vs     = (const float*)d_in[1];
    const float* Cs     = (const float*)d_in[2];
    const float* Us     = (const float*)d_in[3];
    const float* bias   = (const float*)d_in[4];
    const float* gate_w = (const float*)d_in[5];
    float* out = (float*)d_out;

    us* Vf = (us*)d_ws;                                   // 393216 bf16
    us* Uf = Vf + (size_t)CROSS * ELD * DIM;              // 393216
    us* Cf = Uf + (size_t)CROSS * DIM * ELD;              // 49152
    us* Gf = Cf + (size_t)CROSS * ENUM * LR * LR;         // 8192

    swz_all<<<1648, 64, 0, stream>>>(Vs, Cs, Us, gate_w, Vf, Cf, Uf, Gf);
    dcn_fused<<<BATCH / BT, NTHR, 0, stream>>>(x, out, Vf, Cf, Uf, Gf, bias);
}

// Round 4
// 401.912 us; speedup vs baseline: 1.4353x; 1.1006x over previous
//
#include <hip/hip_runtime.h>
#include <hip/hip_bf16.h>

// DCNv2 CrossNet on MI355X — fused 3-layer kernel, v4.
// Key change vs v3: BT=64 rows/block, 8 waves, every wave spans all 64 rows
// (mt_r=4) so each 16B weight fragment feeds 4 MFMAs -> per-CU L2 demand
// ~53 B/cyc (within the 56 B/cyc per-CU share). N-split across waves.
// Padded (non-XOR) LDS layouts: +8-short pad is conflict-free for both
// b128 A-reads and scalar u16 epilogue ops (v3's XOR swizzle regressed).
//
// Shapes: x[32768,512]; Vs[3,4,64,512]; Cs[3,4,64,64]; Us[3,4,512,64];
//         bias[3,512]; gate_w[512,4].

#define CROSS   3
#define ENUM    4
#define LR      64
#define ELD     256     // ENUM*LR
#define DIM     512
#define BATCH   32768
#define BT      64      // batch rows per block
#define NTHR    512     // 8 waves

#define XL_W    520     // 512 + 8 pad (shorts)
#define Y_W     264     // 256 + 8 pad (shorts)

typedef __bf16 bf16x8 __attribute__((ext_vector_type(8)));
typedef float  f32x4  __attribute__((ext_vector_type(4)));
typedef unsigned short us;
typedef unsigned short us4 __attribute__((ext_vector_type(4)));

__device__ __forceinline__ us f2bf(float f) {
    return __builtin_bit_cast(us, (__bf16)f);
}
__device__ __forceinline__ float bf2f(us b) {
    unsigned int u = ((unsigned int)b) << 16;
    return __builtin_bit_cast(float, u);
}
// fast tanh: (e^2x - 1) / (e^2x + 1); inputs bounded by 0.05-scaled weights.
__device__ __forceinline__ float tanh_fast(float x) {
    float t = __expf(2.f * x);
    return (t - 1.f) * __builtin_amdgcn_rcpf(t + 1.f);
}

#define MFMA(a, b, c) __builtin_amdgcn_mfma_f32_16x16x32_bf16(a, b, c, 0, 0, 0)

// ---------------------------------------------------------------------------
// Swizzle prepass: fp32 weights -> bf16 MFMA-B fragment order
// frag[nt][ks][lane][8]: n = nt*16 + (lane&15), k = ks*32 + (lane>>4)*8 + j.
// ---------------------------------------------------------------------------
__global__ __launch_bounds__(64) void swz_all(
    const float* __restrict__ Vs, const float* __restrict__ Cs,
    const float* __restrict__ Us, const float* __restrict__ gw,
    us* __restrict__ Vf, us* __restrict__ Cf,
    us* __restrict__ Uf, us* __restrict__ Gf)
{
    int b = blockIdx.x;
    int lane = threadIdx.x;
    if (b < 768) {                       // V: [3][16 nt][16 ks]
        int i = b >> 8, t = b & 255;
        int nt = t >> 4, ks = t & 15;
        int n  = nt * 16 + (lane & 15);
        int k0 = ks * 32 + (lane >> 4) * 8;
        const float* src = Vs + (size_t)i * ELD * DIM + (size_t)n * DIM + k0;
        us* dst = Vf + (size_t)i * ELD * DIM
                + ((size_t)(nt * 16 + ks) * 64 + lane) * 8;
        #pragma unroll
        for (int j = 0; j < 8; ++j) dst[j] = f2bf(src[j]);
    } else if (b < 1536) {               // U': [3][32 nt][8 ks], k = e*64+l
        int bb = b - 768;
        int i = bb >> 8, t = bb & 255;
        int nt = t >> 3, ks = t & 7;
        int n  = nt * 16 + (lane & 15);            // d
        int k0 = ks * 32 + (lane >> 4) * 8;        // e*64 + l
        int e = k0 >> 6, l0 = k0 & 63;
        const float* src = Us + (size_t)i * ENUM * DIM * LR
                         + (size_t)e * DIM * LR + (size_t)n * LR + l0;
        us* dst = Uf + (size_t)i * DIM * ELD
                + ((size_t)(nt * 8 + ks) * 64 + lane) * 8;
        #pragma unroll
        for (int j = 0; j < 8; ++j) dst[j] = f2bf(src[j]);
    } else if (b < 1632) {               // C: [3][4 e][4 nt][2 ks]
        int bb = b - 1536;
        int i = bb >> 5, rest = bb & 31;
        int e = rest >> 3, t = rest & 7;
        int nt = t >> 1, ks = t & 1;
        int n  = nt * 16 + (lane & 15);
        int k0 = ks * 32 + (lane >> 4) * 8;
        const float* src = Cs + (((size_t)(i * ENUM + e) * LR + n) * LR) + k0;
        us* dst = Cf + (size_t)i * ENUM * LR * LR
                + ((size_t)((e * 4 + nt) * 2 + ks) * 64 + lane) * 8;
        #pragma unroll
        for (int j = 0; j < 8; ++j) dst[j] = f2bf(src[j]);
    } else {                             // gate: [16 ks], n<4 real, rest 0
        int ks = b - 1632;
        int n  = lane & 15;
        int k0 = ks * 32 + (lane >> 4) * 8;
        us* dst = Gf + ((size_t)ks * 64 + lane) * 8;
        #pragma unroll
        for (int j = 0; j < 8; ++j)
            dst[j] = (n < ENUM) ? f2bf(gw[(size_t)(k0 + j) * ENUM + n]) : (us)0;
    }
}

// ---------------------------------------------------------------------------
// Fused 3-layer kernel. Block: 64 rows, 512 threads (8 waves), 1 block/CU.
// Thread element ownership (16x16x32 D-layout, mt in 0..3):
//   row = mt*16 + quad*4 + r,  col(G3) = wave*64 + nt*16 + nl.
// G1: wave owns cols [wave*32,+32) (nt_r=2); wave 0 additionally folds the
// gate GEMM in as one extra B-fragment. G2: expert e = wave>>1, col-half
// h = wave&1. G3: wave owns cols [wave*64,+64) (nt_r=4). All waves span all
// 64 rows (mt_r=4) — this is what sets per-CU L2 weight-stream demand.
// ---------------------------------------------------------------------------
__global__ __launch_bounds__(NTHR, 2) void dcn_fused(
    const float* __restrict__ x,
    float* __restrict__ out,
    const us* __restrict__ Vf,
    const us* __restrict__ Cf,
    const us* __restrict__ Uf,
    const us* __restrict__ Gf,
    const float* __restrict__ bias)
{
    __shared__ us xl_s[BT * XL_W];       // x_l master, bf16 (66.5 KB)
    __shared__ us y_s[BT * Y_W];         // Y then z (33.8 KB)
    __shared__ float g_s[BT * ENUM];     // gate scores (1 KB)

    const int tid  = threadIdx.x;
    const int wave = tid >> 6, lane = tid & 63;
    const int quad = lane >> 4, nl = lane & 15;
    const int row0 = blockIdx.x * BT;

    // ---- stage x -> xl_s (bf16)
    #pragma unroll
    for (int it = 0; it < 16; ++it) {
        int f4 = tid + it * NTHR;            // 0..8191 float4s
        int r = f4 >> 7, c4 = f4 & 127;
        float4 v = *reinterpret_cast<const float4*>(
            x + (size_t)(row0 + r) * DIM + c4 * 4);
        us4 p;
        p[0] = f2bf(v.x); p[1] = f2bf(v.y); p[2] = f2bf(v.z); p[3] = f2bf(v.w);
        *reinterpret_cast<us4*>(&xl_s[r * XL_W + c4 * 4]) = p;
    }
    __syncthreads();

    // ---- x0 packed bf16 in regs (thread's ownership elements)
    unsigned int x0p[4][4][2];
    #pragma unroll
    for (int mt = 0; mt < 4; ++mt)
        #pragma unroll
        for (int nt = 0; nt < 4; ++nt) {
            int rb = mt * 16 + quad * 4;
            int col = wave * 64 + nt * 16 + nl;
            unsigned int b0 = xl_s[(rb + 0) * XL_W + col];
            unsigned int b1 = xl_s[(rb + 1) * XL_W + col];
            unsigned int b2 = xl_s[(rb + 2) * XL_W + col];
            unsigned int b3 = xl_s[(rb + 3) * XL_W + col];
            x0p[mt][nt][0] = b0 | (b1 << 16);
            x0p[mt][nt][1] = b2 | (b3 << 16);
        }

    #pragma unroll 1
    for (int layer = 0; layer < CROSS; ++layer) {
        const us* Vl = Vf + (size_t)layer * ELD * DIM;
        const us* Cl = Cf + (size_t)layer * ENUM * LR * LR;
        const us* Ul = Uf + (size_t)layer * DIM * ELD;
        const float* bl = bias + layer * DIM;

        // ---- GEMM1: Y = tanh(xl @ V^T), wave cols [wave*32,+32); wave 0: gate
        f32x4 acc1[4][2];
        f32x4 gacc[4];
        #pragma unroll
        for (int mt = 0; mt < 4; ++mt) {
            gacc[mt] = (f32x4)0.f;
            acc1[mt][0] = (f32x4)0.f;
            acc1[mt][1] = (f32x4)0.f;
        }
        #pragma unroll 4
        for (int ks = 0; ks < 16; ++ks) {
            bf16x8 a[4];
            #pragma unroll
            for (int mt = 0; mt < 4; ++mt)
                a[mt] = *reinterpret_cast<const bf16x8*>(
                    &xl_s[(mt * 16 + nl) * XL_W + ks * 32 + quad * 8]);
            #pragma unroll
            for (int nt = 0; nt < 2; ++nt) {
                bf16x8 bfr = *reinterpret_cast<const bf16x8*>(
                    &Vl[((size_t)((wave * 2 + nt) * 16 + ks) * 64 + lane) * 8]);
                #pragma unroll
                for (int mt = 0; mt < 4; ++mt)
                    acc1[mt][nt] = MFMA(a[mt], bfr, acc1[mt][nt]);
            }
            if (wave == 0) {
                bf16x8 bg = *reinterpret_cast<const bf16x8*>(
                    &Gf[((size_t)ks * 64 + lane) * 8]);
                #pragma unroll
                for (int mt = 0; mt < 4; ++mt)
                    gacc[mt] = MFMA(a[mt], bg, gacc[mt]);
            }
        }
        #pragma unroll
        for (int mt = 0; mt < 4; ++mt)
            #pragma unroll
            for (int r = 0; r < 4; ++r) {
                int row = mt * 16 + quad * 4 + r;
                #pragma unroll
                for (int nt = 0; nt < 2; ++nt)
                    y_s[row * Y_W + wave * 32 + nt * 16 + nl] =
                        f2bf(tanh_fast(acc1[mt][nt][r]));
            }
        if (wave == 0 && nl < ENUM) {
            #pragma unroll
            for (int mt = 0; mt < 4; ++mt)
                #pragma unroll
                for (int r = 0; r < 4; ++r)
                    g_s[(mt * 16 + quad * 4 + r) * ENUM + nl] = gacc[mt][r];
        }
        __syncthreads();

        // ---- GEMM2: z = g ⊙ tanh(Y_e @ C_e^T). e = wave>>1, half = wave&1.
        const int e = wave >> 1, h = wave & 1;
        f32x4 acc2[4][2];
        #pragma unroll
        for (int mt = 0; mt < 4; ++mt) {
            acc2[mt][0] = (f32x4)0.f;
            acc2[mt][1] = (f32x4)0.f;
        }
        #pragma unroll
        for (int ks = 0; ks < 2; ++ks) {
            bf16x8 a[4];
            #pragma unroll
            for (int mt = 0; mt < 4; ++mt)
                a[mt] = *reinterpret_cast<const bf16x8*>(
                    &y_s[(mt * 16 + nl) * Y_W + e * 64 + ks * 32 + quad * 8]);
            #pragma unroll
            for (int nt = 0; nt < 2; ++nt) {
                bf16x8 bfr = *reinterpret_cast<const bf16x8*>(
                    &Cl[((size_t)((e * 4 + h * 2 + nt) * 2 + ks) * 64 + lane) * 8]);
                #pragma unroll
                for (int mt = 0; mt < 4; ++mt)
                    acc2[mt][nt] = MFMA(a[mt], bfr, acc2[mt][nt]);
            }
        }
        __syncthreads();   // all Y reads complete before in-place overwrite
        #pragma unroll
        for (int mt = 0; mt < 4; ++mt)
            #pragma unroll
            for (int r = 0; r < 4; ++r) {
                int row = mt * 16 + quad * 4 + r;
                float gv = g_s[row * ENUM + e];
                #pragma unroll
                for (int nt = 0; nt < 2; ++nt)
                    y_s[row * Y_W + e * 64 + h * 32 + nt * 16 + nl] =
                        f2bf(tanh_fast(acc2[mt][nt][r]) * gv);
            }
        __syncthreads();

        // ---- Gv = sum_e g[row][e]
        float Gv[4][4];
        #pragma unroll
        for (int mt = 0; mt < 4; ++mt)
            #pragma unroll
            for (int r = 0; r < 4; ++r) {
                int row = mt * 16 + quad * 4 + r;
                f32x4 g4 = *reinterpret_cast<const f32x4*>(&g_s[row * ENUM]);
                Gv[mt][r] = g4[0] + g4[1] + g4[2] + g4[3];
            }

        // ---- GEMM3: core = z @ U'^T, wave cols [wave*64,+64), K=256
        f32x4 acc3[4][4];
        #pragma unroll
        for (int mt = 0; mt < 4; ++mt)
            #pragma unroll
            for (int nt = 0; nt < 4; ++nt) acc3[mt][nt] = (f32x4)0.f;
        #pragma unroll 2
        for (int ks = 0; ks < 8; ++ks) {
            bf16x8 a[4];
            #pragma unroll
            for (int mt = 0; mt < 4; ++mt)
                a[mt] = *reinterpret_cast<const bf16x8*>(
                    &y_s[(mt * 16 + nl) * Y_W + ks * 32 + quad * 8]);
            #pragma unroll
            for (int nt = 0; nt < 4; ++nt) {
                bf16x8 bfr = *reinterpret_cast<const bf16x8*>(
                    &Ul[((size_t)((wave * 4 + nt) * 8 + ks) * 64 + lane) * 8]);
                #pragma unroll
                for (int mt = 0; mt < 4; ++mt)
                    acc3[mt][nt] = MFMA(a[mt], bfr, acc3[mt][nt]);
            }
        }

        // ---- epilogue: xl = xl + x0 * (core + bias*G)
        #pragma unroll
        for (int nt = 0; nt < 4; ++nt) {
            int col = wave * 64 + nt * 16 + nl;
            float bc = bl[col];
            #pragma unroll
            for (int mt = 0; mt < 4; ++mt)
                #pragma unroll
                for (int r = 0; r < 4; ++r) {
                    int row = mt * 16 + quad * 4 + r;
                    float x0v = bf2f(
                        (us)(x0p[mt][nt][r >> 1] >> ((r & 1) * 16)));
                    float xlo = bf2f(xl_s[row * XL_W + col]);
                    float res = xlo
                              + x0v * (acc3[mt][nt][r] + bc * Gv[mt][r]);
                    if (layer == CROSS - 1)
                        out[(size_t)(row0 + row) * DIM + col] = res;
                    else
                        xl_s[row * XL_W + col] = f2bf(res);
                }
        }
        if (layer < CROSS - 1) __syncthreads();
    }
}

// ---------------------------------------------------------------------------
extern "C" void kernel_launch(void* const* d_in, const int* in_sizes, int n_in,
                              void* d_out, int out_size, void* d_ws,
                              size_t ws_size, hipStream_t stream) {
    const float* x      = (const float*)d_in[0];
    const float* Vs     = (const float*)d_in[1];
    const float* Cs     = (const float*)d_in[2];
    const float* Us     = (const float*)d_in[3];
    const float* bias   = (const float*)d_in[4];
    const float* gate_w = (const float*)d_in[5];
    float* out = (float*)d_out;

    us* Vf = (us*)d_ws;                                   // 393216 bf16
    us* Uf = Vf + (size_t)CROSS * ELD * DIM;              // 393216
    us* Cf = Uf + (size_t)CROSS * DIM * ELD;              // 49152
    us* Gf = Cf + (size_t)CROSS * ENUM * LR * LR;         // 8192

    swz_all<<<1648, 64, 0, stream>>>(Vs, Cs, Us, gate_w, Vf, Cf, Uf, Gf);
    dcn_fused<<<BATCH / BT, NTHR, 0, stream>>>(x, out, Vf, Cf, Uf, Gf, bias);
}